// Round 8
// baseline (99.547 us; speedup 1.0000x reference)
//
#include <hip/hip_runtime.h>
#include <stdint.h>

typedef __attribute__((ext_vector_type(8))) short short8;      // 8 x bf16 (MFMA A/B frag)
typedef __attribute__((ext_vector_type(4))) float f32x4;       // MFMA acc frag
typedef __attribute__((ext_vector_type(4))) float f4;
typedef __attribute__((ext_vector_type(4))) unsigned short us4;

typedef unsigned short ushort_t;

__device__ __forceinline__ ushort_t f2bf(float f) {
    union { float f; uint32_t u; } c; c.f = f;
    uint32_t u = c.u;
    uint32_t r = u + 0x7fffu + ((u >> 16) & 1u);   // RNE
    return (ushort_t)(r >> 16);
}
__device__ __forceinline__ float bf2f(ushort_t h) {
    union { uint32_t u; float f; } c; c.u = ((uint32_t)h) << 16;
    return c.f;
}

// async global->LDS, 16B per lane; LDS dest = wave-uniform base + lane*16
typedef const __attribute__((address_space(1))) unsigned int as1_uint;
typedef __attribute__((address_space(3))) unsigned int as3_uint;
__device__ __forceinline__ void gload_lds16(const void* g, void* l) {
    __builtin_amdgcn_global_load_lds((as1_uint*)g, (as3_uint*)l, 16, 0, 0);
}

// LDS tile [256 rows][64 cols] bf16, XOR-swizzled: element (r,c) lives at
// ushort index r*64 + (c ^ ((r&7)<<3)). LDS stays linear for global_load_lds;
// the inverse permutation is applied on the GLOBAL source chunk (rule #21).
#define SWIDX(r, c) ((r) * 64 + ((c) ^ (((r) & 7) << 3)))

// ---------------------------------------------------------------------------
// Weight prep: B^T ([N][K]) layouts.
// ---------------------------------------------------------------------------
__global__ void prep_weights(const float* __restrict__ gate_W, const float* __restrict__ B_W,
                             const float* __restrict__ C_W, const float* __restrict__ out_W,
                             ushort_t* __restrict__ W1t_hi, ushort_t* __restrict__ W1t_lo,
                             ushort_t* __restrict__ outWt, ushort_t* __restrict__ Ct)
{
    int idx = blockIdx.x * 256 + threadIdx.x;
    int stride = gridDim.x * 256;
    for (int i = idx; i < 1024 * 1024; i += stride) {
        int nn = i >> 10, kk = i & 1023;
        outWt[i] = f2bf(out_W[kk * 1024 + nn]);
    }
    for (int i = idx; i < 128 * 1024; i += stride) {
        int nn = i >> 10, kk = i & 1023;
        float v = (nn < 64) ? gate_W[kk * 64 + nn] : B_W[kk * 64 + (nn - 64)];
        ushort_t h = f2bf(v);
        W1t_hi[i] = h;
        W1t_lo[i] = f2bf(v - bf2f(h));
    }
    for (int i = idx; i < 1024 * 64; i += stride) {
        int nn = i >> 6, kk = i & 63;
        Ct[i] = f2bf(C_W[kk * 1024 + nn]);
    }
}

// ---------------------------------------------------------------------------
// P1: Z^T[n][s] = sum_k W1[k][n] * x[s][k], split precision (3-pass bf16),
// split-K (2 chunks of 512). Writes x_hi (bf16 of x) as a staging byproduct.
// ---------------------------------------------------------------------------
__global__ __launch_bounds__(256, 2)
void p1_kernel(const float* __restrict__ x,
               const ushort_t* __restrict__ W1t_hi, const ushort_t* __restrict__ W1t_lo,
               ushort_t* __restrict__ x_hi, float* __restrict__ Zpart)
{
    __shared__ ushort_t Ash[128 * 64];
    __shared__ ushort_t Asl[128 * 64];
    __shared__ ushort_t Bsh[64 * 64];
    __shared__ ushort_t Bsl[64 * 64];

    const int tid = threadIdx.x;
    const int wave = tid >> 6, lane = tid & 63;
    const int wm = wave >> 1, wn = wave & 1;
    const int s0 = blockIdx.x * 64;
    const int kc = blockIdx.y;

    f32x4 acc[4][2];
#pragma unroll
    for (int i = 0; i < 4; i++)
#pragma unroll
        for (int j = 0; j < 2; j++) { f32x4 z = {0.f,0.f,0.f,0.f}; acc[i][j] = z; }

    for (int kt = 0; kt < 8; ++kt) {
        const int k0 = kc * 512 + kt * 64;
#pragma unroll
        for (int p = 0; p < 4; ++p) {
            int c = p * 256 + wave * 64 + lane;
            int row = c >> 3, col = (c & 7) * 8;
            gload_lds16(W1t_hi + (size_t)row * 1024 + k0 + col,
                        &Ash[(p * 256 + wave * 64) * 8]);
            gload_lds16(W1t_lo + (size_t)row * 1024 + k0 + col,
                        &Asl[(p * 256 + wave * 64) * 8]);
        }
#pragma unroll
        for (int p = 0; p < 4; ++p) {
            int f = tid + p * 256;
            int row = f >> 4, col = (f & 15) * 4;
            f4 v = *(const f4*)(x + (size_t)(s0 + row) * 1024 + k0 + col);
            us4 hi, lo;
#pragma unroll
            for (int j = 0; j < 4; j++) {
                ushort_t h = f2bf(v[j]);
                hi[j] = h;
                lo[j] = f2bf(v[j] - bf2f(h));
            }
            *(us4*)&Bsh[row * 64 + col] = hi;
            *(us4*)&Bsl[row * 64 + col] = lo;
            *(us4*)(x_hi + (size_t)(s0 + row) * 1024 + k0 + col) = hi;
        }
        __syncthreads();
#pragma unroll
        for (int kk = 0; kk < 2; ++kk) {
            const int kb = kk * 32 + (lane >> 4) * 8;
            short8 ah[4], al[4], bh[2], bl[2];
#pragma unroll
            for (int fm = 0; fm < 4; fm++) {
                int r = wm * 64 + fm * 16 + (lane & 15);
                ah[fm] = *(const short8*)&Ash[r * 64 + kb];
                al[fm] = *(const short8*)&Asl[r * 64 + kb];
            }
#pragma unroll
            for (int fn = 0; fn < 2; fn++) {
                int r = wn * 32 + fn * 16 + (lane & 15);
                bh[fn] = *(const short8*)&Bsh[r * 64 + kb];
                bl[fn] = *(const short8*)&Bsl[r * 64 + kb];
            }
#pragma unroll
            for (int fm = 0; fm < 4; fm++)
#pragma unroll
                for (int fn = 0; fn < 2; fn++) {
                    acc[fm][fn] = __builtin_amdgcn_mfma_f32_16x16x32_bf16(ah[fm], bh[fn], acc[fm][fn], 0, 0, 0);
                    acc[fm][fn] = __builtin_amdgcn_mfma_f32_16x16x32_bf16(al[fm], bh[fn], acc[fm][fn], 0, 0, 0);
                    acc[fm][fn] = __builtin_amdgcn_mfma_f32_16x16x32_bf16(ah[fm], bl[fn], acc[fm][fn], 0, 0, 0);
                }
        }
        __syncthreads();
    }
#pragma unroll
    for (int fm = 0; fm < 4; fm++) {
#pragma unroll
        for (int fn = 0; fn < 2; fn++) {
            int scol = s0 + wn * 32 + fn * 16 + (lane & 15);
            int b = scol >> 12, sb = scol & 4095;
            int nbase = wm * 64 + fm * 16 + ((lane >> 4) << 2);
#pragma unroll
            for (int r = 0; r < 4; r++) {
                Zpart[((size_t)kc * 512 + b * 128 + nbase + r) * 4096 + sb] = acc[fm][fn][r];
            }
        }
    }
}

// ---------------------------------------------------------------------------
// Scan: combine split-K partials, gate = sigmoid(zg+bias), h_t = a_t*h + b_t.
// Output hT[b*64+n][s] bf16.
// ---------------------------------------------------------------------------
__global__ __launch_bounds__(256)
void scan_kernel(const float* __restrict__ Zpart, const float* __restrict__ gate_b,
                 ushort_t* __restrict__ hT)
{
    __shared__ float SA[256], SB[256];
    const int bn = blockIdx.x;
    const int t = threadIdx.x;
    const int b = bn >> 6, n = bn & 63;
    const float gb = gate_b[n];
    const float* g0 = Zpart + ((size_t)(b * 128 + n)) * 4096;
    const float* g1 = g0 + (size_t)512 * 4096;
    const float* b0 = Zpart + ((size_t)(b * 128 + 64 + n)) * 4096;
    const float* b1 = b0 + (size_t)512 * 4096;
    const int sb = t * 16;

    float a[16], bb[16];
#pragma unroll
    for (int q = 0; q < 4; q++) {
        f4 vg0 = *(const f4*)(g0 + sb + q * 4);
        f4 vg1 = *(const f4*)(g1 + sb + q * 4);
        f4 vb0 = *(const f4*)(b0 + sb + q * 4);
        f4 vb1 = *(const f4*)(b1 + sb + q * 4);
#pragma unroll
        for (int j = 0; j < 4; j++) {
            a[q * 4 + j] = 1.f / (1.f + __expf(-(vg0[j] + vg1[j] + gb)));
            bb[q * 4 + j] = vb0[j] + vb1[j];
        }
    }
    float A = 1.f, Bv = 0.f;
#pragma unroll
    for (int i = 0; i < 16; i++) { Bv = a[i] * Bv + bb[i]; A *= a[i]; }
    SA[t] = A; SB[t] = Bv;
    __syncthreads();
    for (int off = 1; off < 256; off <<= 1) {
        float a1 = 1.f, b1v = 0.f;
        if (t >= off) { a1 = SA[t - off]; b1v = SB[t - off]; }
        float a2 = SA[t], b2 = SB[t];
        __syncthreads();
        SA[t] = a1 * a2;
        SB[t] = a2 * b1v + b2;
        __syncthreads();
    }
    float h = (t == 0) ? 0.f : SB[t - 1];
    ushort_t ov[16];
#pragma unroll
    for (int i = 0; i < 16; i++) {
        h = a[i] * h + bb[i];
        ov[i] = f2bf(h);
    }
    ushort_t* dst = hT + (size_t)bn * 4096 + sb;
#pragma unroll
    for (int q = 0; q < 4; q++) {
        us4 o; o[0]=ov[q*4]; o[1]=ov[q*4+1]; o[2]=ov[q*4+2]; o[3]=ov[q*4+3];
        *(us4*)(dst + q * 4) = o;
    }
}

// ---------------------------------------------------------------------------
// gemm_out256: out = (h@C_W) * sigmoid(x_hi @ outWt^T).
// 256x256 tile, BK=64, 512 threads (8 waves = 2M x 4N), double-buffered LDS,
// T2 XOR-swizzle. R8 schedule: hoisted addressing + register prefetch +
// ONE barrier per phase:
//   phase q: {vmcnt wait if due; barrier; stage (ptr+=64); ds_read prefetch
//   for NEXT phase (base+imm, zero VALU); MFMA(q) on regs prefetched last
//   phase (compiler emits counted lgkmcnt — rule: no inline lgkm asm)}.
//   Stage order during tile t: q0->Ah1(t+1)|buf^1, q1->B0(t+2)|buf,
//   q2->B1(t+2)|buf, q3->Ah0(t+2)|buf. Waits: q1 vmcnt(8) [retires Ah1(t)],
//   q3 vmcnt(6) [retires B(t+1)+Ah0(t+1)]. Ledger verified incl. prologue
//   (7 stages, vmcnt(6)) and tail (t=14: q3 vmcnt(2); t=15: q1 vmcnt(0)).
//   Hazard audit: every LDS region's last reader phase strictly precedes its
//   writer phase with >=1 barrier between (reads complete before reader's
//   MFMA, which precedes the next barrier).
// ---------------------------------------------------------------------------
__global__ __launch_bounds__(512, 2)
void gemm_out256(const ushort_t* __restrict__ x_hi, const ushort_t* __restrict__ outWt,
                 const ushort_t* __restrict__ hT, const ushort_t* __restrict__ Ct,
                 float* __restrict__ out)
{
    __shared__ ushort_t As[2][256 * 64];   // 64 KiB
    __shared__ ushort_t Bs[2][256 * 64];   // 64 KiB

    const int tid = threadIdx.x;
    const int wave = tid >> 6, lane = tid & 63;
    const int wm = wave >> 2;          // 0..1
    const int wn = wave & 3;           // 0..3

    // XCD chunking: XCD k (= flat&7) owns m-tiles 8k..8k+7, sweeps n within.
    const int flat = blockIdx.x;
    const int swz = (flat & 7) * 32 + (flat >> 3);
    const int m0 = (swz >> 2) * 256;
    const int n0 = (swz & 3) * 256;

    const int lcol0 = (lane >> 4) * 8;
    const int lrow = lane & 15;
    const int lxor = (lrow & 7) << 3;

    // per-lane LDS read offsets (elements); q/mm/fn become immediate adds
    const int aOff0 = (wm * 32 + lrow) * 64 + (lcol0 ^ lxor);
    const int aOff1 = (wm * 32 + lrow) * 64 + ((32 + lcol0) ^ lxor);
    const int bOff0 = (wn * 64 + lrow) * 64 + (lcol0 ^ lxor);
    const int bOff1 = (wn * 64 + lrow) * 64 + ((32 + lcol0) ^ lxor);

    // persistent global stage streams (advance +64 elements per stage)
    const int rl0 = tid >> 3;                       // 0..63
    const int col0 = ((tid & 7) ^ (rl0 & 7)) << 3;  // inverse-swizzled source
    const ushort_t* gB0a = outWt + (size_t)(n0 + rl0) * 1024 + col0;
    const ushort_t* gB0b = gB0a + 64 * 1024;
    const ushort_t* gB1a = outWt + (size_t)(n0 + 128 + rl0) * 1024 + col0;
    const ushort_t* gB1b = gB1a + 64 * 1024;
    const ushort_t* gA0a = x_hi + (size_t)(m0 + rl0) * 1024 + col0;
    const ushort_t* gA0b = gA0a + 64 * 1024;
    const ushort_t* gA1a = x_hi + (size_t)(m0 + 128 + rl0) * 1024 + col0;
    const ushort_t* gA1b = gA1a + 64 * 1024;

    auto STG = [&](const ushort_t*& ga, const ushort_t*& gb, ushort_t* ldsbase) {
        gload_lds16(ga, ldsbase + wave * 512);
        gload_lds16(gb, ldsbase + 4096 + wave * 512);
        ga += 64; gb += 64;
    };

    f32x4 acc[8][4];
#pragma unroll
    for (int i = 0; i < 8; i++)
#pragma unroll
        for (int j = 0; j < 4; j++) { f32x4 z = {0.f,0.f,0.f,0.f}; acc[i][j] = z; }

    // prologue: 7 stages in steady issue order, counted drain, prefetch Aq0(0)
    STG(gB0a, gB0b, &Bs[0][0]);        // B0(0)
    STG(gB1a, gB1b, &Bs[0][8192]);     // B1(0)
    STG(gA0a, gA0b, &As[0][0]);        // Ah0(0)
    STG(gA1a, gA1b, &As[0][8192]);     // Ah1(0)
    STG(gB0a, gB0b, &Bs[1][0]);        // B0(1)
    STG(gB1a, gB1b, &Bs[1][8192]);     // B1(1)
    STG(gA0a, gA0b, &As[1][0]);        // Ah0(1)
    asm volatile("s_waitcnt vmcnt(6)" ::: "memory");
    __builtin_amdgcn_s_barrier();

    short8 aF[2][2], aN[2][2];
#pragma unroll
    for (int mm = 0; mm < 2; ++mm) {
        aF[mm][0] = *(const short8*)&As[0][aOff0 + mm * 1024];
        aF[mm][1] = *(const short8*)&As[0][aOff1 + mm * 1024];
    }

#define MFMA_Q(q)                                                                  \
    do {                                                                           \
        __builtin_amdgcn_s_setprio(1);                                             \
        _Pragma("unroll") for (int mm = 0; mm < 2; ++mm)                           \
            _Pragma("unroll") for (int fn = 0; fn < 4; ++fn) {                     \
                acc[2*(q)+mm][fn] = __builtin_amdgcn_mfma_f32_16x16x32_bf16(       \
                    aF[mm][0], bfr[fn][0], acc[2*(q)+mm][fn], 0, 0, 0);            \
                acc[2*(q)+mm][fn] = __builtin_amdgcn_mfma_f32_16x16x32_bf16(       \
                    aF[mm][1], bfr[fn][1], acc[2*(q)+mm][fn], 0, 0, 0);            \
            }                                                                      \
        __builtin_amdgcn_s_setprio(0);                                             \
    } while (0)

#define ACOPY()                                                                    \
    do { aF[0][0]=aN[0][0]; aF[0][1]=aN[0][1]; aF[1][0]=aN[1][0]; aF[1][1]=aN[1][1]; } while (0)

    for (int t = 0; t < 16; ++t) {
        const int bc = t & 1;
        const ushort_t* aP0 = &As[bc][aOff0];
        const ushort_t* aP1 = &As[bc][aOff1];
        const ushort_t* bP0 = &Bs[bc][bOff0];
        const ushort_t* bP1 = &Bs[bc][bOff1];
        const ushort_t* nA0 = &As[bc ^ 1][aOff0];
        const ushort_t* nA1 = &As[bc ^ 1][aOff1];
        short8 bfr[4][2];

        // ---- q0: MFMA Aq0 ----
        __builtin_amdgcn_s_barrier();
        if (t < 15) STG(gA1a, gA1b, &As[bc ^ 1][8192]);        // Ah1(t+1)
#pragma unroll
        for (int fn = 0; fn < 4; ++fn) {
            bfr[fn][0] = *(const short8*)(bP0 + fn * 1024);
            bfr[fn][1] = *(const short8*)(bP1 + fn * 1024);
        }
#pragma unroll
        for (int mm = 0; mm < 2; ++mm) {
            aN[mm][0] = *(const short8*)(aP0 + 4096 + mm * 1024);   // Aq1
            aN[mm][1] = *(const short8*)(aP1 + 4096 + mm * 1024);
        }
        MFMA_Q(0);
        ACOPY();

        // ---- q1: MFMA Aq1 ----
        if (t < 15) { asm volatile("s_waitcnt vmcnt(8)" ::: "memory"); }
        else        { asm volatile("s_waitcnt vmcnt(0)" ::: "memory"); }
        __builtin_amdgcn_s_barrier();
        if (t < 14) STG(gB0a, gB0b, &Bs[bc][0]);               // B0(t+2)
#pragma unroll
        for (int mm = 0; mm < 2; ++mm) {
            aN[mm][0] = *(const short8*)(aP0 + 2 * 4096 + mm * 1024);  // Aq2
            aN[mm][1] = *(const short8*)(aP1 + 2 * 4096 + mm * 1024);
        }
        MFMA_Q(1);
        ACOPY();

        // ---- q2: MFMA Aq2 ----
        __builtin_amdgcn_s_barrier();
        if (t < 14) STG(gB1a, gB1b, &Bs[bc][8192]);            // B1(t+2)
#pragma unroll
        for (int mm = 0; mm < 2; ++mm) {
            aN[mm][0] = *(const short8*)(aP0 + 3 * 4096 + mm * 1024);  // Aq3
            aN[mm][1] = *(const short8*)(aP1 + 3 * 4096 + mm * 1024);
        }
        MFMA_Q(2);
        ACOPY();

        // ---- q3: MFMA Aq3 ----
        if (t < 14)       { asm volatile("s_waitcnt vmcnt(6)" ::: "memory"); }
        else if (t == 14) { asm volatile("s_waitcnt vmcnt(2)" ::: "memory"); }
        __builtin_amdgcn_s_barrier();
        if (t < 14) STG(gA0a, gA0b, &As[bc][0]);               // Ah0(t+2)
        if (t < 15) {
#pragma unroll
            for (int mm = 0; mm < 2; ++mm) {
                aN[mm][0] = *(const short8*)(nA0 + mm * 1024);  // Aq0(t+1)
                aN[mm][1] = *(const short8*)(nA1 + mm * 1024);
            }
        }
        MFMA_Q(3);
        if (t < 15) ACOPY();
    }
#undef MFMA_Q
#undef ACOPY

    // ---------- fused y epilogue: y = h @ C_W on this tile (K = 64) ----------
    const int b64 = (m0 >> 12) * 64;
    const int sb0 = m0 & 4095;
    // Bs[0] <- Ct rows n0..n0+255 (gload_lds, pre-swizzled source)
#pragma unroll
    for (int p = 0; p < 4; ++p) {
        int c = p * 512 + wave * 64 + lane;
        int row = c >> 3;
        int col = (((c & 7) ^ (row & 7)) << 3);
        gload_lds16(Ct + (size_t)(n0 + row) * 64 + col,
                    &Bs[0][(p * 512 + wave * 64) * 8]);
    }
    // As[0] <- transpose(hT): As[m_local][kn], swizzled ds_writes
#pragma unroll
    for (int p = 0; p < 4; ++p) {
        int c = tid + p * 512;           // 2048 chunks: kn = c>>5, mc = c&31
        int kn = c >> 5, mc = c & 31;
        short8 v = *(const short8*)(hT + (size_t)(b64 + kn) * 4096 + sb0 + mc * 8);
#pragma unroll
        for (int j = 0; j < 8; ++j)
            As[0][SWIDX(mc * 8 + j, kn)] = (ushort_t)v[j];
    }
    __syncthreads();

    short8 by[4][2];
#pragma unroll
    for (int fn = 0; fn < 4; fn++)
#pragma unroll
        for (int kk = 0; kk < 2; kk++) {
            int r = wn * 64 + fn * 16 + lrow;
            by[fn][kk] = *(const short8*)&Bs[0][SWIDX(r, kk * 32 + lcol0)];
        }

#pragma unroll
    for (int g = 0; g < 4; g++) {        // register-sliced: 2 m-frags at a time
        f32x4 ty[2][4];
#pragma unroll
        for (int mm = 0; mm < 2; mm++)
#pragma unroll
            for (int fn = 0; fn < 4; fn++) { f32x4 z = {0.f,0.f,0.f,0.f}; ty[mm][fn] = z; }
#pragma unroll
        for (int mm = 0; mm < 2; mm++) {
            int r = g * 64 + wm * 32 + mm * 16 + lrow;
            short8 a0 = *(const short8*)&As[0][SWIDX(r, lcol0)];
            short8 a1 = *(const short8*)&As[0][SWIDX(r, 32 + lcol0)];
#pragma unroll
            for (int fn = 0; fn < 4; fn++) {
                ty[mm][fn] = __builtin_amdgcn_mfma_f32_16x16x32_bf16(a0, by[fn][0], ty[mm][fn], 0, 0, 0);
                ty[mm][fn] = __builtin_amdgcn_mfma_f32_16x16x32_bf16(a1, by[fn][1], ty[mm][fn], 0, 0, 0);
            }
        }
#pragma unroll
        for (int mm = 0; mm < 2; mm++)
#pragma unroll
            for (int fn = 0; fn < 4; fn++) {
                int col = n0 + wn * 64 + fn * 16 + lrow;
                int rbase = m0 + g * 64 + wm * 32 + mm * 16 + ((lane >> 4) << 2);
#pragma unroll
                for (int r = 0; r < 4; r++) {
                    float og = 1.f / (1.f + __expf(-acc[g * 2 + mm][fn][r]));
                    out[(size_t)(rbase + r) * 1024 + col] = ty[mm][fn][r] * og;
                }
            }
    }
}

// ---------------------------------------------------------------------------
extern "C" void kernel_launch(void* const* d_in, const int* in_sizes, int n_in,
                              void* d_out, int out_size, void* d_ws, size_t ws_size,
                              hipStream_t stream)
{
    const float* x      = (const float*)d_in[0];   // (4,4096,1024)
    const float* gate_W = (const float*)d_in[1];   // (1024,64)
    const float* gate_b = (const float*)d_in[2];   // (64,)
    const float* B_W    = (const float*)d_in[3];   // (1024,64)
    const float* C_W    = (const float*)d_in[4];   // (64,1024)
    const float* out_W  = (const float*)d_in[5];   // (1024,1024)
    // d_in[6] mix_weight cancels (h_next == h_final); d_in[7] chunk_size unused.
    float* out = (float*)d_out;

    char* ws = (char*)d_ws;
    float*    Zpart  = (float*)(ws + 0);            // 16 MiB [2][512][4096] fp32
    ushort_t* hT     = (ushort_t*)(ws + 16777216);  //  2 MiB [256][4096]
    ushort_t* x_hi   = (ushort_t*)(ws + 18874368);  // 32 MiB [16384][1024]
    ushort_t* W1t_hi = (ushort_t*)(ws + 52428800);  // [128][1024]
    ushort_t* W1t_lo = (ushort_t*)(ws + 52690944);
    ushort_t* outWt  = (ushort_t*)(ws + 52953088);  // [1024][1024]
    ushort_t* Ct     = (ushort_t*)(ws + 55050240);  // [1024][64]

    prep_weights<<<512, 256, 0, stream>>>(gate_W, B_W, C_W, out_W,
                                          W1t_hi, W1t_lo, outWt, Ct);

    p1_kernel<<<dim3(256, 2), 256, 0, stream>>>(x, W1t_hi, W1t_lo, x_hi, Zpart);

    scan_kernel<<<256, 256, 0, stream>>>(Zpart, gate_b, hT);

    gemm_out256<<<256, 512, 0, stream>>>(x_hi, outWt, hT, Ct, out);
}

// Round 9
// 96.316 us; speedup vs baseline: 1.0336x; 1.0336x over previous
//
#include <hip/hip_runtime.h>
#include <stdint.h>

typedef __attribute__((ext_vector_type(8))) short short8;      // 8 x bf16 (MFMA A/B frag)
typedef __attribute__((ext_vector_type(4))) float f32x4;       // MFMA acc frag
typedef __attribute__((ext_vector_type(4))) float f4;
typedef __attribute__((ext_vector_type(4))) unsigned short us4;

typedef unsigned short ushort_t;

__device__ __forceinline__ ushort_t f2bf(float f) {
    union { float f; uint32_t u; } c; c.f = f;
    uint32_t u = c.u;
    uint32_t r = u + 0x7fffu + ((u >> 16) & 1u);   // RNE
    return (ushort_t)(r >> 16);
}
__device__ __forceinline__ float bf2f(ushort_t h) {
    union { uint32_t u; float f; } c; c.u = ((uint32_t)h) << 16;
    return c.f;
}

// async global->LDS, 16B per lane; LDS dest = wave-uniform base + lane*16
typedef const __attribute__((address_space(1))) unsigned int as1_uint;
typedef __attribute__((address_space(3))) unsigned int as3_uint;
__device__ __forceinline__ void gload_lds16(const void* g, void* l) {
    __builtin_amdgcn_global_load_lds((as1_uint*)g, (as3_uint*)l, 16, 0, 0);
}

// LDS tile [256 rows][64 cols] bf16, XOR-swizzled: element (r,c) lives at
// ushort index r*64 + (c ^ ((r&7)<<3)). LDS stays linear for global_load_lds;
// the inverse permutation is applied on the GLOBAL source chunk (rule #21).
#define SWIDX(r, c) ((r) * 64 + ((c) ^ (((r) & 7) << 3)))

// ---------------------------------------------------------------------------
// Weight prep: B^T ([N][K]) layouts.
// ---------------------------------------------------------------------------
__global__ void prep_weights(const float* __restrict__ gate_W, const float* __restrict__ B_W,
                             const float* __restrict__ C_W, const float* __restrict__ out_W,
                             ushort_t* __restrict__ W1t_hi, ushort_t* __restrict__ W1t_lo,
                             ushort_t* __restrict__ outWt, ushort_t* __restrict__ Ct)
{
    int idx = blockIdx.x * 256 + threadIdx.x;
    int stride = gridDim.x * 256;
    for (int i = idx; i < 1024 * 1024; i += stride) {
        int nn = i >> 10, kk = i & 1023;
        outWt[i] = f2bf(out_W[kk * 1024 + nn]);
    }
    for (int i = idx; i < 128 * 1024; i += stride) {
        int nn = i >> 10, kk = i & 1023;
        float v = (nn < 64) ? gate_W[kk * 64 + nn] : B_W[kk * 64 + (nn - 64)];
        ushort_t h = f2bf(v);
        W1t_hi[i] = h;
        W1t_lo[i] = f2bf(v - bf2f(h));
    }
    for (int i = idx; i < 1024 * 64; i += stride) {
        int nn = i >> 6, kk = i & 63;
        Ct[i] = f2bf(C_W[kk * 1024 + nn]);
    }
}

// ---------------------------------------------------------------------------
// P1: Z^T[n][s] = sum_k W1[k][n] * x[s][k], split precision (3-pass bf16),
// split-K (2 chunks of 512). Writes x_hi (bf16 of x) as a staging byproduct.
// ---------------------------------------------------------------------------
__global__ __launch_bounds__(256, 2)
void p1_kernel(const float* __restrict__ x,
               const ushort_t* __restrict__ W1t_hi, const ushort_t* __restrict__ W1t_lo,
               ushort_t* __restrict__ x_hi, float* __restrict__ Zpart)
{
    __shared__ ushort_t Ash[128 * 64];
    __shared__ ushort_t Asl[128 * 64];
    __shared__ ushort_t Bsh[64 * 64];
    __shared__ ushort_t Bsl[64 * 64];

    const int tid = threadIdx.x;
    const int wave = tid >> 6, lane = tid & 63;
    const int wm = wave >> 1, wn = wave & 1;
    const int s0 = blockIdx.x * 64;
    const int kc = blockIdx.y;

    f32x4 acc[4][2];
#pragma unroll
    for (int i = 0; i < 4; i++)
#pragma unroll
        for (int j = 0; j < 2; j++) { f32x4 z = {0.f,0.f,0.f,0.f}; acc[i][j] = z; }

    for (int kt = 0; kt < 8; ++kt) {
        const int k0 = kc * 512 + kt * 64;
#pragma unroll
        for (int p = 0; p < 4; ++p) {
            int c = p * 256 + wave * 64 + lane;
            int row = c >> 3, col = (c & 7) * 8;
            gload_lds16(W1t_hi + (size_t)row * 1024 + k0 + col,
                        &Ash[(p * 256 + wave * 64) * 8]);
            gload_lds16(W1t_lo + (size_t)row * 1024 + k0 + col,
                        &Asl[(p * 256 + wave * 64) * 8]);
        }
#pragma unroll
        for (int p = 0; p < 4; ++p) {
            int f = tid + p * 256;
            int row = f >> 4, col = (f & 15) * 4;
            f4 v = *(const f4*)(x + (size_t)(s0 + row) * 1024 + k0 + col);
            us4 hi, lo;
#pragma unroll
            for (int j = 0; j < 4; j++) {
                ushort_t h = f2bf(v[j]);
                hi[j] = h;
                lo[j] = f2bf(v[j] - bf2f(h));
            }
            *(us4*)&Bsh[row * 64 + col] = hi;
            *(us4*)&Bsl[row * 64 + col] = lo;
            *(us4*)(x_hi + (size_t)(s0 + row) * 1024 + k0 + col) = hi;
        }
        __syncthreads();
#pragma unroll
        for (int kk = 0; kk < 2; ++kk) {
            const int kb = kk * 32 + (lane >> 4) * 8;
            short8 ah[4], al[4], bh[2], bl[2];
#pragma unroll
            for (int fm = 0; fm < 4; fm++) {
                int r = wm * 64 + fm * 16 + (lane & 15);
                ah[fm] = *(const short8*)&Ash[r * 64 + kb];
                al[fm] = *(const short8*)&Asl[r * 64 + kb];
            }
#pragma unroll
            for (int fn = 0; fn < 2; fn++) {
                int r = wn * 32 + fn * 16 + (lane & 15);
                bh[fn] = *(const short8*)&Bsh[r * 64 + kb];
                bl[fn] = *(const short8*)&Bsl[r * 64 + kb];
            }
#pragma unroll
            for (int fm = 0; fm < 4; fm++)
#pragma unroll
                for (int fn = 0; fn < 2; fn++) {
                    acc[fm][fn] = __builtin_amdgcn_mfma_f32_16x16x32_bf16(ah[fm], bh[fn], acc[fm][fn], 0, 0, 0);
                    acc[fm][fn] = __builtin_amdgcn_mfma_f32_16x16x32_bf16(al[fm], bh[fn], acc[fm][fn], 0, 0, 0);
                    acc[fm][fn] = __builtin_amdgcn_mfma_f32_16x16x32_bf16(ah[fm], bl[fn], acc[fm][fn], 0, 0, 0);
                }
        }
        __syncthreads();
    }
#pragma unroll
    for (int fm = 0; fm < 4; fm++) {
#pragma unroll
        for (int fn = 0; fn < 2; fn++) {
            int scol = s0 + wn * 32 + fn * 16 + (lane & 15);
            int b = scol >> 12, sb = scol & 4095;
            int nbase = wm * 64 + fm * 16 + ((lane >> 4) << 2);
#pragma unroll
            for (int r = 0; r < 4; r++) {
                Zpart[((size_t)kc * 512 + b * 128 + nbase + r) * 4096 + sb] = acc[fm][fn][r];
            }
        }
    }
}

// ---------------------------------------------------------------------------
// Scan: combine split-K partials, gate = sigmoid(zg+bias), h_t = a_t*h + b_t.
// Output hT[b*64+n][s] bf16.
// ---------------------------------------------------------------------------
__global__ __launch_bounds__(256)
void scan_kernel(const float* __restrict__ Zpart, const float* __restrict__ gate_b,
                 ushort_t* __restrict__ hT)
{
    __shared__ float SA[256], SB[256];
    const int bn = blockIdx.x;
    const int t = threadIdx.x;
    const int b = bn >> 6, n = bn & 63;
    const float gb = gate_b[n];
    const float* g0 = Zpart + ((size_t)(b * 128 + n)) * 4096;
    const float* g1 = g0 + (size_t)512 * 4096;
    const float* b0 = Zpart + ((size_t)(b * 128 + 64 + n)) * 4096;
    const float* b1 = b0 + (size_t)512 * 4096;
    const int sb = t * 16;

    float a[16], bb[16];
#pragma unroll
    for (int q = 0; q < 4; q++) {
        f4 vg0 = *(const f4*)(g0 + sb + q * 4);
        f4 vg1 = *(const f4*)(g1 + sb + q * 4);
        f4 vb0 = *(const f4*)(b0 + sb + q * 4);
        f4 vb1 = *(const f4*)(b1 + sb + q * 4);
#pragma unroll
        for (int j = 0; j < 4; j++) {
            a[q * 4 + j] = 1.f / (1.f + __expf(-(vg0[j] + vg1[j] + gb)));
            bb[q * 4 + j] = vb0[j] + vb1[j];
        }
    }
    float A = 1.f, Bv = 0.f;
#pragma unroll
    for (int i = 0; i < 16; i++) { Bv = a[i] * Bv + bb[i]; A *= a[i]; }
    SA[t] = A; SB[t] = Bv;
    __syncthreads();
    for (int off = 1; off < 256; off <<= 1) {
        float a1 = 1.f, b1v = 0.f;
        if (t >= off) { a1 = SA[t - off]; b1v = SB[t - off]; }
        float a2 = SA[t], b2 = SB[t];
        __syncthreads();
        SA[t] = a1 * a2;
        SB[t] = a2 * b1v + b2;
        __syncthreads();
    }
    float h = (t == 0) ? 0.f : SB[t - 1];
    ushort_t ov[16];
#pragma unroll
    for (int i = 0; i < 16; i++) {
        h = a[i] * h + bb[i];
        ov[i] = f2bf(h);
    }
    ushort_t* dst = hT + (size_t)bn * 4096 + sb;
#pragma unroll
    for (int q = 0; q < 4; q++) {
        us4 o; o[0]=ov[q*4]; o[1]=ov[q*4+1]; o[2]=ov[q*4+2]; o[3]=ov[q*4+3];
        *(us4*)(dst + q * 4) = o;
    }
}

// ---------------------------------------------------------------------------
// gemm_out256: out = (h@C_W) * sigmoid(x_hi @ outWt^T).
// 256x256 tile, BK=64, 512 threads (8 waves = 2M x 4N), double-buffered LDS,
// T2 XOR-swizzle. R9 = R6's proven schedule (stages ONLY into buf^1 — never
// the buffer being read) with improved stage order for +1 phase of cover:
//   q0: stage B0(t+1)            q1: stage B1(t+1), A0(t+1)
//   q2: stage A1(t+1)            q3: (no stage)
//   waits: q1 vmcnt(6) retires A1(t)  [3 phases cover]
//          q3 vmcnt(2) retires B0,B1,A0(t+1)  [2-3 phases cover]
//   Tail: t=15 no stages, q1 vmcnt(0). Hoisted addressing (R8): per-lane LDS
//   offsets + persistent global stream pointers (+64/step).
// ---------------------------------------------------------------------------
__global__ __launch_bounds__(512, 2)
void gemm_out256(const ushort_t* __restrict__ x_hi, const ushort_t* __restrict__ outWt,
                 const ushort_t* __restrict__ hT, const ushort_t* __restrict__ Ct,
                 float* __restrict__ out)
{
    __shared__ ushort_t As[2][256 * 64];   // 64 KiB
    __shared__ ushort_t Bs[2][256 * 64];   // 64 KiB

    const int tid = threadIdx.x;
    const int wave = tid >> 6, lane = tid & 63;
    const int wm = wave >> 2;          // 0..1
    const int wn = wave & 3;           // 0..3

    // XCD chunking: XCD k (= flat&7) owns m-tiles 8k..8k+7, sweeps n within.
    const int flat = blockIdx.x;
    const int swz = (flat & 7) * 32 + (flat >> 3);
    const int m0 = (swz >> 2) * 256;
    const int n0 = (swz & 3) * 256;

    const int lcol0 = (lane >> 4) * 8;
    const int lrow = lane & 15;
    const int lxor = (lrow & 7) << 3;

    // per-lane LDS read offsets (elements); q/mm/fn become immediate adds
    const int aOff0 = (wm * 32 + lrow) * 64 + (lcol0 ^ lxor);
    const int aOff1 = (wm * 32 + lrow) * 64 + ((32 + lcol0) ^ lxor);
    const int bOff0 = (wn * 64 + lrow) * 64 + (lcol0 ^ lxor);
    const int bOff1 = (wn * 64 + lrow) * 64 + ((32 + lcol0) ^ lxor);

    // persistent global stage streams (advance +64 elements per stage)
    const int rl0 = tid >> 3;                       // 0..63
    const int col0 = ((tid & 7) ^ (rl0 & 7)) << 3;  // inverse-swizzled source
    const ushort_t* gB0a = outWt + (size_t)(n0 + rl0) * 1024 + col0;
    const ushort_t* gB0b = gB0a + 64 * 1024;
    const ushort_t* gB1a = outWt + (size_t)(n0 + 128 + rl0) * 1024 + col0;
    const ushort_t* gB1b = gB1a + 64 * 1024;
    const ushort_t* gA0a = x_hi + (size_t)(m0 + rl0) * 1024 + col0;
    const ushort_t* gA0b = gA0a + 64 * 1024;
    const ushort_t* gA1a = x_hi + (size_t)(m0 + 128 + rl0) * 1024 + col0;
    const ushort_t* gA1b = gA1a + 64 * 1024;

    auto STG = [&](const ushort_t*& ga, const ushort_t*& gb, ushort_t* ldsbase) {
        gload_lds16(ga, ldsbase + wave * 512);
        gload_lds16(gb, ldsbase + 4096 + wave * 512);
        ga += 64; gb += 64;
    };

    f32x4 acc[8][4];
#pragma unroll
    for (int i = 0; i < 8; i++)
#pragma unroll
        for (int j = 0; j < 4; j++) { f32x4 z = {0.f,0.f,0.f,0.f}; acc[i][j] = z; }

    // prologue: stage all of tile 0 in steady order; retire B0,B1,A0; A1 flies.
    STG(gB0a, gB0b, &Bs[0][0]);        // B0(0)
    STG(gB1a, gB1b, &Bs[0][8192]);     // B1(0)
    STG(gA0a, gA0b, &As[0][0]);        // A0(0)
    STG(gA1a, gA1b, &As[0][8192]);     // A1(0)
    asm volatile("s_waitcnt vmcnt(2)" ::: "memory");
    __builtin_amdgcn_s_barrier();

#define MFMA_Q(q)                                                                  \
    do {                                                                           \
        __builtin_amdgcn_s_setprio(1);                                             \
        _Pragma("unroll") for (int mm = 0; mm < 2; ++mm)                           \
            _Pragma("unroll") for (int fn = 0; fn < 4; ++fn) {                     \
                acc[2*(q)+mm][fn] = __builtin_amdgcn_mfma_f32_16x16x32_bf16(       \
                    afr[mm][0], bfr[fn][0], acc[2*(q)+mm][fn], 0, 0, 0);           \
                acc[2*(q)+mm][fn] = __builtin_amdgcn_mfma_f32_16x16x32_bf16(       \
                    afr[mm][1], bfr[fn][1], acc[2*(q)+mm][fn], 0, 0, 0);           \
            }                                                                      \
        __builtin_amdgcn_s_setprio(0);                                             \
    } while (0)

    for (int t = 0; t < 16; ++t) {
        const int bc = t & 1;
        const ushort_t* as = &As[bc][0];
        const ushort_t* bs = &Bs[bc][0];
        short8 bfr[4][2], afr[2][2];

        // ---- q0 ----
#pragma unroll
        for (int fn = 0; fn < 4; ++fn) {
            bfr[fn][0] = *(const short8*)(bs + bOff0 + fn * 1024);
            bfr[fn][1] = *(const short8*)(bs + bOff1 + fn * 1024);
        }
#pragma unroll
        for (int mm = 0; mm < 2; ++mm) {
            afr[mm][0] = *(const short8*)(as + aOff0 + mm * 1024);
            afr[mm][1] = *(const short8*)(as + aOff1 + mm * 1024);
        }
        if (t < 15) STG(gB0a, gB0b, &Bs[bc ^ 1][0]);           // B0(t+1)
        __builtin_amdgcn_s_barrier();
        asm volatile("s_waitcnt lgkmcnt(0)" ::: "memory");
        __builtin_amdgcn_sched_barrier(0);
        MFMA_Q(0);
        __builtin_amdgcn_s_barrier();

        // ---- q1 ----
#pragma unroll
        for (int mm = 0; mm < 2; ++mm) {
            afr[mm][0] = *(const short8*)(as + aOff0 + 4096 + mm * 1024);
            afr[mm][1] = *(const short8*)(as + aOff1 + 4096 + mm * 1024);
        }
        if (t < 15) {
            STG(gB1a, gB1b, &Bs[bc ^ 1][8192]);                // B1(t+1)
            STG(gA0a, gA0b, &As[bc ^ 1][0]);                   // A0(t+1)
        }
        __builtin_amdgcn_s_barrier();
        asm volatile("s_waitcnt lgkmcnt(0)" ::: "memory");
        __builtin_amdgcn_sched_barrier(0);
        MFMA_Q(1);
        if (t < 15) { asm volatile("s_waitcnt vmcnt(6)" ::: "memory"); }
        else        { asm volatile("s_waitcnt vmcnt(0)" ::: "memory"); }
        __builtin_amdgcn_s_barrier();

        // ---- q2 ----
#pragma unroll
        for (int mm = 0; mm < 2; ++mm) {
            afr[mm][0] = *(const short8*)(as + aOff0 + 2 * 4096 + mm * 1024);
            afr[mm][1] = *(const short8*)(as + aOff1 + 2 * 4096 + mm * 1024);
        }
        if (t < 15) STG(gA1a, gA1b, &As[bc ^ 1][8192]);        // A1(t+1)
        __builtin_amdgcn_s_barrier();
        asm volatile("s_waitcnt lgkmcnt(0)" ::: "memory");
        __builtin_amdgcn_sched_barrier(0);
        MFMA_Q(2);
        __builtin_amdgcn_s_barrier();

        // ---- q3 ----
#pragma unroll
        for (int mm = 0; mm < 2; ++mm) {
            afr[mm][0] = *(const short8*)(as + aOff0 + 3 * 4096 + mm * 1024);
            afr[mm][1] = *(const short8*)(as + aOff1 + 3 * 4096 + mm * 1024);
        }
        __builtin_amdgcn_s_barrier();
        asm volatile("s_waitcnt lgkmcnt(0)" ::: "memory");
        __builtin_amdgcn_sched_barrier(0);
        MFMA_Q(3);
        if (t < 15) { asm volatile("s_waitcnt vmcnt(2)" ::: "memory"); }
        __builtin_amdgcn_s_barrier();
    }
#undef MFMA_Q

    // ---------- fused y epilogue: y = h @ C_W on this tile (K = 64) ----------
    const int b64 = (m0 >> 12) * 64;
    const int sb0 = m0 & 4095;
    // Bs[0] <- Ct rows n0..n0+255 (gload_lds, pre-swizzled source)
#pragma unroll
    for (int p = 0; p < 4; ++p) {
        int c = p * 512 + wave * 64 + lane;
        int row = c >> 3;
        int col = (((c & 7) ^ (row & 7)) << 3);
        gload_lds16(Ct + (size_t)(n0 + row) * 64 + col,
                    &Bs[0][(p * 512 + wave * 64) * 8]);
    }
    // As[0] <- transpose(hT): As[m_local][kn], swizzled ds_writes
#pragma unroll
    for (int p = 0; p < 4; ++p) {
        int c = tid + p * 512;           // 2048 chunks: kn = c>>5, mc = c&31
        int kn = c >> 5, mc = c & 31;
        short8 v = *(const short8*)(hT + (size_t)(b64 + kn) * 4096 + sb0 + mc * 8);
#pragma unroll
        for (int j = 0; j < 8; ++j)
            As[0][SWIDX(mc * 8 + j, kn)] = (ushort_t)v[j];
    }
    __syncthreads();

    short8 by[4][2];
#pragma unroll
    for (int fn = 0; fn < 4; fn++)
#pragma unroll
        for (int kk = 0; kk < 2; kk++) {
            int r = wn * 64 + fn * 16 + lrow;
            by[fn][kk] = *(const short8*)&Bs[0][SWIDX(r, kk * 32 + lcol0)];
        }

#pragma unroll
    for (int g = 0; g < 4; g++) {        // register-sliced: 2 m-frags at a time
        f32x4 ty[2][4];
#pragma unroll
        for (int mm = 0; mm < 2; mm++)
#pragma unroll
            for (int fn = 0; fn < 4; fn++) { f32x4 z = {0.f,0.f,0.f,0.f}; ty[mm][fn] = z; }
#pragma unroll
        for (int mm = 0; mm < 2; mm++) {
            int r = g * 64 + wm * 32 + mm * 16 + lrow;
            short8 a0 = *(const short8*)&As[0][SWIDX(r, lcol0)];
            short8 a1 = *(const short8*)&As[0][SWIDX(r, 32 + lcol0)];
#pragma unroll
            for (int fn = 0; fn < 4; fn++) {
                ty[mm][fn] = __builtin_amdgcn_mfma_f32_16x16x32_bf16(a0, by[fn][0], ty[mm][fn], 0, 0, 0);
                ty[mm][fn] = __builtin_amdgcn_mfma_f32_16x16x32_bf16(a1, by[fn][1], ty[mm][fn], 0, 0, 0);
            }
        }
#pragma unroll
        for (int mm = 0; mm < 2; mm++)
#pragma unroll
            for (int fn = 0; fn < 4; fn++) {
                int col = n0 + wn * 64 + fn * 16 + lrow;
                int rbase = m0 + g * 64 + wm * 32 + mm * 16 + ((lane >> 4) << 2);
#pragma unroll
                for (int r = 0; r < 4; r++) {
                    float og = 1.f / (1.f + __expf(-acc[g * 2 + mm][fn][r]));
                    out[(size_t)(rbase + r) * 1024 + col] = ty[mm][fn][r] * og;
                }
            }
    }
}

// ---------------------------------------------------------------------------
extern "C" void kernel_launch(void* const* d_in, const int* in_sizes, int n_in,
                              void* d_out, int out_size, void* d_ws, size_t ws_size,
                              hipStream_t stream)
{
    const float* x      = (const float*)d_in[0];   // (4,4096,1024)
    const float* gate_W = (const float*)d_in[1];   // (1024,64)
    const float* gate_b = (const float*)d_in[2];   // (64,)
    const float* B_W    = (const float*)d_in[3];   // (1024,64)
    const float* C_W    = (const float*)d_in[4];   // (64,1024)
    const float* out_W  = (const float*)d_in[5];   // (1024,1024)
    // d_in[6] mix_weight cancels (h_next == h_final); d_in[7] chunk_size unused.
    float* out = (float*)d_out;

    char* ws = (char*)d_ws;
    float*    Zpart  = (float*)(ws + 0);            // 16 MiB [2][512][4096] fp32
    ushort_t* hT     = (ushort_t*)(ws + 16777216);  //  2 MiB [256][4096]
    ushort_t* x_hi   = (ushort_t*)(ws + 18874368);  // 32 MiB [16384][1024]
    ushort_t* W1t_hi = (ushort_t*)(ws + 52428800);  // [128][1024]
    ushort_t* W1t_lo = (ushort_t*)(ws + 52690944);
    ushort_t* outWt  = (ushort_t*)(ws + 52953088);  // [1024][1024]
    ushort_t* Ct     = (ushort_t*)(ws + 55050240);  // [1024][64]

    prep_weights<<<512, 256, 0, stream>>>(gate_W, B_W, C_W, out_W,
                                          W1t_hi, W1t_lo, outWt, Ct);

    p1_kernel<<<dim3(256, 2), 256, 0, stream>>>(x, W1t_hi, W1t_lo, x_hi, Zpart);

    scan_kernel<<<256, 256, 0, stream>>>(Zpart, gate_b, hT);

    gemm_out256<<<256, 512, 0, stream>>>(x_hi, outWt, hT, Ct, out);
}

// Round 10
// 91.855 us; speedup vs baseline: 1.0837x; 1.0486x over previous
//
#include <hip/hip_runtime.h>
#include <stdint.h>

typedef __attribute__((ext_vector_type(8))) short short8;      // 8 x bf16 (MFMA A/B frag)
typedef __attribute__((ext_vector_type(4))) float f32x4;       // MFMA acc frag
typedef __attribute__((ext_vector_type(4))) float f4;
typedef __attribute__((ext_vector_type(4))) unsigned short us4;

typedef unsigned short ushort_t;

__device__ __forceinline__ ushort_t f2bf(float f) {
    union { float f; uint32_t u; } c; c.f = f;
    uint32_t u = c.u;
    uint32_t r = u + 0x7fffu + ((u >> 16) & 1u);   // RNE
    return (ushort_t)(r >> 16);
}
__device__ __forceinline__ float bf2f(ushort_t h) {
    union { uint32_t u; float f; } c; c.u = ((uint32_t)h) << 16;
    return c.f;
}

// async global->LDS, 16B per lane; LDS dest = wave-uniform base + lane*16
typedef const __attribute__((address_space(1))) unsigned int as1_uint;
typedef __attribute__((address_space(3))) unsigned int as3_uint;
__device__ __forceinline__ void gload_lds16(const void* g, void* l) {
    __builtin_amdgcn_global_load_lds((as1_uint*)g, (as3_uint*)l, 16, 0, 0);
}

// LDS tile [256 rows][64 cols] bf16, XOR-swizzled: element (r,c) lives at
// ushort index r*64 + (c ^ ((r&7)<<3)). LDS stays linear for global_load_lds;
// the inverse permutation is applied on the GLOBAL source chunk (rule #21).
#define SWIDX(r, c) ((r) * 64 + ((c) ^ (((r) & 7) << 3)))

// ---------------------------------------------------------------------------
// Weight prep: B^T ([N][K]) layouts.
// ---------------------------------------------------------------------------
__global__ void prep_weights(const float* __restrict__ gate_W, const float* __restrict__ B_W,
                             const float* __restrict__ C_W, const float* __restrict__ out_W,
                             ushort_t* __restrict__ W1t_hi, ushort_t* __restrict__ W1t_lo,
                             ushort_t* __restrict__ outWt, ushort_t* __restrict__ Ct)
{
    int idx = blockIdx.x * 256 + threadIdx.x;
    int stride = gridDim.x * 256;
    for (int i = idx; i < 1024 * 1024; i += stride) {
        int nn = i >> 10, kk = i & 1023;
        outWt[i] = f2bf(out_W[kk * 1024 + nn]);
    }
    for (int i = idx; i < 128 * 1024; i += stride) {
        int nn = i >> 10, kk = i & 1023;
        float v = (nn < 64) ? gate_W[kk * 64 + nn] : B_W[kk * 64 + (nn - 64)];
        ushort_t h = f2bf(v);
        W1t_hi[i] = h;
        W1t_lo[i] = f2bf(v - bf2f(h));
    }
    for (int i = idx; i < 1024 * 64; i += stride) {
        int nn = i >> 6, kk = i & 63;
        Ct[i] = f2bf(C_W[kk * 1024 + nn]);
    }
}

// ---------------------------------------------------------------------------
// P1: Z^T[n][s] = sum_k W1[k][n] * x[s][k], 2-PASS split precision:
//   acc = Whi*xhi + Wlo*xhi   (W-lo kept: it's DMA'd, zero VALU cost;
//   x-lo pass dropped: delta-z ~ 0.002 abs -> ~0.03 on output, within budget)
// Split-K (2 chunks of 512). Writes x_hi (bf16 of x) as a staging byproduct.
// ---------------------------------------------------------------------------
__global__ __launch_bounds__(256, 2)
void p1_kernel(const float* __restrict__ x,
               const ushort_t* __restrict__ W1t_hi, const ushort_t* __restrict__ W1t_lo,
               ushort_t* __restrict__ x_hi, float* __restrict__ Zpart)
{
    __shared__ ushort_t Ash[128 * 64];
    __shared__ ushort_t Asl[128 * 64];
    __shared__ ushort_t Bsh[64 * 64];

    const int tid = threadIdx.x;
    const int wave = tid >> 6, lane = tid & 63;
    const int wm = wave >> 1, wn = wave & 1;
    const int s0 = blockIdx.x * 64;
    const int kc = blockIdx.y;

    f32x4 acc[4][2];
#pragma unroll
    for (int i = 0; i < 4; i++)
#pragma unroll
        for (int j = 0; j < 2; j++) { f32x4 z = {0.f,0.f,0.f,0.f}; acc[i][j] = z; }

    for (int kt = 0; kt < 8; ++kt) {
        const int k0 = kc * 512 + kt * 64;
#pragma unroll
        for (int p = 0; p < 4; ++p) {
            int c = p * 256 + wave * 64 + lane;
            int row = c >> 3, col = (c & 7) * 8;
            gload_lds16(W1t_hi + (size_t)row * 1024 + k0 + col,
                        &Ash[(p * 256 + wave * 64) * 8]);
            gload_lds16(W1t_lo + (size_t)row * 1024 + k0 + col,
                        &Asl[(p * 256 + wave * 64) * 8]);
        }
#pragma unroll
        for (int p = 0; p < 4; ++p) {
            int f = tid + p * 256;
            int row = f >> 4, col = (f & 15) * 4;
            f4 v = *(const f4*)(x + (size_t)(s0 + row) * 1024 + k0 + col);
            us4 hi;
#pragma unroll
            for (int j = 0; j < 4; j++) hi[j] = f2bf(v[j]);
            *(us4*)&Bsh[row * 64 + col] = hi;
            *(us4*)(x_hi + (size_t)(s0 + row) * 1024 + k0 + col) = hi;
        }
        __syncthreads();
#pragma unroll
        for (int kk = 0; kk < 2; ++kk) {
            const int kb = kk * 32 + (lane >> 4) * 8;
            short8 ah[4], al[4], bh[2];
#pragma unroll
            for (int fm = 0; fm < 4; fm++) {
                int r = wm * 64 + fm * 16 + (lane & 15);
                ah[fm] = *(const short8*)&Ash[r * 64 + kb];
                al[fm] = *(const short8*)&Asl[r * 64 + kb];
            }
#pragma unroll
            for (int fn = 0; fn < 2; fn++) {
                int r = wn * 32 + fn * 16 + (lane & 15);
                bh[fn] = *(const short8*)&Bsh[r * 64 + kb];
            }
#pragma unroll
            for (int fm = 0; fm < 4; fm++)
#pragma unroll
                for (int fn = 0; fn < 2; fn++) {
                    acc[fm][fn] = __builtin_amdgcn_mfma_f32_16x16x32_bf16(ah[fm], bh[fn], acc[fm][fn], 0, 0, 0);
                    acc[fm][fn] = __builtin_amdgcn_mfma_f32_16x16x32_bf16(al[fm], bh[fn], acc[fm][fn], 0, 0, 0);
                }
        }
        __syncthreads();
    }
#pragma unroll
    for (int fm = 0; fm < 4; fm++) {
#pragma unroll
        for (int fn = 0; fn < 2; fn++) {
            int scol = s0 + wn * 32 + fn * 16 + (lane & 15);
            int b = scol >> 12, sb = scol & 4095;
            int nbase = wm * 64 + fm * 16 + ((lane >> 4) << 2);
#pragma unroll
            for (int r = 0; r < 4; r++) {
                Zpart[((size_t)kc * 512 + b * 128 + nbase + r) * 4096 + sb] = acc[fm][fn][r];
            }
        }
    }
}

// ---------------------------------------------------------------------------
// Scan: combine split-K partials, gate = sigmoid(zg+bias), h_t = a_t*h + b_t.
// Output hT[b*64+n][s] bf16.
// ---------------------------------------------------------------------------
__global__ __launch_bounds__(256)
void scan_kernel(const float* __restrict__ Zpart, const float* __restrict__ gate_b,
                 ushort_t* __restrict__ hT)
{
    __shared__ float SA[256], SB[256];
    const int bn = blockIdx.x;
    const int t = threadIdx.x;
    const int b = bn >> 6, n = bn & 63;
    const float gb = gate_b[n];
    const float* g0 = Zpart + ((size_t)(b * 128 + n)) * 4096;
    const float* g1 = g0 + (size_t)512 * 4096;
    const float* b0 = Zpart + ((size_t)(b * 128 + 64 + n)) * 4096;
    const float* b1 = b0 + (size_t)512 * 4096;
    const int sb = t * 16;

    float a[16], bb[16];
#pragma unroll
    for (int q = 0; q < 4; q++) {
        f4 vg0 = *(const f4*)(g0 + sb + q * 4);
        f4 vg1 = *(const f4*)(g1 + sb + q * 4);
        f4 vb0 = *(const f4*)(b0 + sb + q * 4);
        f4 vb1 = *(const f4*)(b1 + sb + q * 4);
#pragma unroll
        for (int j = 0; j < 4; j++) {
            a[q * 4 + j] = 1.f / (1.f + __expf(-(vg0[j] + vg1[j] + gb)));
            bb[q * 4 + j] = vb0[j] + vb1[j];
        }
    }
    float A = 1.f, Bv = 0.f;
#pragma unroll
    for (int i = 0; i < 16; i++) { Bv = a[i] * Bv + bb[i]; A *= a[i]; }
    SA[t] = A; SB[t] = Bv;
    __syncthreads();
    for (int off = 1; off < 256; off <<= 1) {
        float a1 = 1.f, b1v = 0.f;
        if (t >= off) { a1 = SA[t - off]; b1v = SB[t - off]; }
        float a2 = SA[t], b2 = SB[t];
        __syncthreads();
        SA[t] = a1 * a2;
        SB[t] = a2 * b1v + b2;
        __syncthreads();
    }
    float h = (t == 0) ? 0.f : SB[t - 1];
    ushort_t ov[16];
#pragma unroll
    for (int i = 0; i < 16; i++) {
        h = a[i] * h + bb[i];
        ov[i] = f2bf(h);
    }
    ushort_t* dst = hT + (size_t)bn * 4096 + sb;
#pragma unroll
    for (int q = 0; q < 4; q++) {
        us4 o; o[0]=ov[q*4]; o[1]=ov[q*4+1]; o[2]=ov[q*4+2]; o[3]=ov[q*4+3];
        *(us4*)(dst + q * 4) = o;
    }
}

// ---------------------------------------------------------------------------
// gemm_out256: out = (h@C_W) * sigmoid(x_hi @ outWt^T).
// 256x256 tile, BK=64, 512 threads (8 waves = 2M x 4N), double-buffered LDS,
// T2 XOR-swizzle. FROZEN R9 schedule (best known, ~58.5 us): stages ONLY into
// buf^1; q0: B0(t+1), q1: B1(t+1)+A0(t+1), q2: A1(t+1); waits q1 vmcnt(6),
// q3 vmcnt(2); hoisted addressing.
// ---------------------------------------------------------------------------
__global__ __launch_bounds__(512, 2)
void gemm_out256(const ushort_t* __restrict__ x_hi, const ushort_t* __restrict__ outWt,
                 const ushort_t* __restrict__ hT, const ushort_t* __restrict__ Ct,
                 float* __restrict__ out)
{
    __shared__ ushort_t As[2][256 * 64];   // 64 KiB
    __shared__ ushort_t Bs[2][256 * 64];   // 64 KiB

    const int tid = threadIdx.x;
    const int wave = tid >> 6, lane = tid & 63;
    const int wm = wave >> 2;          // 0..1
    const int wn = wave & 3;           // 0..3

    // XCD chunking: XCD k (= flat&7) owns m-tiles 8k..8k+7, sweeps n within.
    const int flat = blockIdx.x;
    const int swz = (flat & 7) * 32 + (flat >> 3);
    const int m0 = (swz >> 2) * 256;
    const int n0 = (swz & 3) * 256;

    const int lcol0 = (lane >> 4) * 8;
    const int lrow = lane & 15;
    const int lxor = (lrow & 7) << 3;

    // per-lane LDS read offsets (elements); q/mm/fn become immediate adds
    const int aOff0 = (wm * 32 + lrow) * 64 + (lcol0 ^ lxor);
    const int aOff1 = (wm * 32 + lrow) * 64 + ((32 + lcol0) ^ lxor);
    const int bOff0 = (wn * 64 + lrow) * 64 + (lcol0 ^ lxor);
    const int bOff1 = (wn * 64 + lrow) * 64 + ((32 + lcol0) ^ lxor);

    // persistent global stage streams (advance +64 elements per stage)
    const int rl0 = tid >> 3;                       // 0..63
    const int col0 = ((tid & 7) ^ (rl0 & 7)) << 3;  // inverse-swizzled source
    const ushort_t* gB0a = outWt + (size_t)(n0 + rl0) * 1024 + col0;
    const ushort_t* gB0b = gB0a + 64 * 1024;
    const ushort_t* gB1a = outWt + (size_t)(n0 + 128 + rl0) * 1024 + col0;
    const ushort_t* gB1b = gB1a + 64 * 1024;
    const ushort_t* gA0a = x_hi + (size_t)(m0 + rl0) * 1024 + col0;
    const ushort_t* gA0b = gA0a + 64 * 1024;
    const ushort_t* gA1a = x_hi + (size_t)(m0 + 128 + rl0) * 1024 + col0;
    const ushort_t* gA1b = gA1a + 64 * 1024;

    auto STG = [&](const ushort_t*& ga, const ushort_t*& gb, ushort_t* ldsbase) {
        gload_lds16(ga, ldsbase + wave * 512);
        gload_lds16(gb, ldsbase + 4096 + wave * 512);
        ga += 64; gb += 64;
    };

    f32x4 acc[8][4];
#pragma unroll
    for (int i = 0; i < 8; i++)
#pragma unroll
        for (int j = 0; j < 4; j++) { f32x4 z = {0.f,0.f,0.f,0.f}; acc[i][j] = z; }

    // prologue: stage all of tile 0 in steady order; retire B0,B1,A0; A1 flies.
    STG(gB0a, gB0b, &Bs[0][0]);        // B0(0)
    STG(gB1a, gB1b, &Bs[0][8192]);     // B1(0)
    STG(gA0a, gA0b, &As[0][0]);        // A0(0)
    STG(gA1a, gA1b, &As[0][8192]);     // A1(0)
    asm volatile("s_waitcnt vmcnt(2)" ::: "memory");
    __builtin_amdgcn_s_barrier();

#define MFMA_Q(q)                                                                  \
    do {                                                                           \
        __builtin_amdgcn_s_setprio(1);                                             \
        _Pragma("unroll") for (int mm = 0; mm < 2; ++mm)                           \
            _Pragma("unroll") for (int fn = 0; fn < 4; ++fn) {                     \
                acc[2*(q)+mm][fn] = __builtin_amdgcn_mfma_f32_16x16x32_bf16(       \
                    afr[mm][0], bfr[fn][0], acc[2*(q)+mm][fn], 0, 0, 0);           \
                acc[2*(q)+mm][fn] = __builtin_amdgcn_mfma_f32_16x16x32_bf16(       \
                    afr[mm][1], bfr[fn][1], acc[2*(q)+mm][fn], 0, 0, 0);           \
            }                                                                      \
        __builtin_amdgcn_s_setprio(0);                                             \
    } while (0)

    for (int t = 0; t < 16; ++t) {
        const int bc = t & 1;
        const ushort_t* as = &As[bc][0];
        const ushort_t* bs = &Bs[bc][0];
        short8 bfr[4][2], afr[2][2];

        // ---- q0 ----
#pragma unroll
        for (int fn = 0; fn < 4; ++fn) {
            bfr[fn][0] = *(const short8*)(bs + bOff0 + fn * 1024);
            bfr[fn][1] = *(const short8*)(bs + bOff1 + fn * 1024);
        }
#pragma unroll
        for (int mm = 0; mm < 2; ++mm) {
            afr[mm][0] = *(const short8*)(as + aOff0 + mm * 1024);
            afr[mm][1] = *(const short8*)(as + aOff1 + mm * 1024);
        }
        if (t < 15) STG(gB0a, gB0b, &Bs[bc ^ 1][0]);           // B0(t+1)
        __builtin_amdgcn_s_barrier();
        asm volatile("s_waitcnt lgkmcnt(0)" ::: "memory");
        __builtin_amdgcn_sched_barrier(0);
        MFMA_Q(0);
        __builtin_amdgcn_s_barrier();

        // ---- q1 ----
#pragma unroll
        for (int mm = 0; mm < 2; ++mm) {
            afr[mm][0] = *(const short8*)(as + aOff0 + 4096 + mm * 1024);
            afr[mm][1] = *(const short8*)(as + aOff1 + 4096 + mm * 1024);
        }
        if (t < 15) {
            STG(gB1a, gB1b, &Bs[bc ^ 1][8192]);                // B1(t+1)
            STG(gA0a, gA0b, &As[bc ^ 1][0]);                   // A0(t+1)
        }
        __builtin_amdgcn_s_barrier();
        asm volatile("s_waitcnt lgkmcnt(0)" ::: "memory");
        __builtin_amdgcn_sched_barrier(0);
        MFMA_Q(1);
        if (t < 15) { asm volatile("s_waitcnt vmcnt(6)" ::: "memory"); }
        else        { asm volatile("s_waitcnt vmcnt(0)" ::: "memory"); }
        __builtin_amdgcn_s_barrier();

        // ---- q2 ----
#pragma unroll
        for (int mm = 0; mm < 2; ++mm) {
            afr[mm][0] = *(const short8*)(as + aOff0 + 2 * 4096 + mm * 1024);
            afr[mm][1] = *(const short8*)(as + aOff1 + 2 * 4096 + mm * 1024);
        }
        if (t < 15) STG(gA1a, gA1b, &As[bc ^ 1][8192]);        // A1(t+1)
        __builtin_amdgcn_s_barrier();
        asm volatile("s_waitcnt lgkmcnt(0)" ::: "memory");
        __builtin_amdgcn_sched_barrier(0);
        MFMA_Q(2);
        __builtin_amdgcn_s_barrier();

        // ---- q3 ----
#pragma unroll
        for (int mm = 0; mm < 2; ++mm) {
            afr[mm][0] = *(const short8*)(as + aOff0 + 3 * 4096 + mm * 1024);
            afr[mm][1] = *(const short8*)(as + aOff1 + 3 * 4096 + mm * 1024);
        }
        __builtin_amdgcn_s_barrier();
        asm volatile("s_waitcnt lgkmcnt(0)" ::: "memory");
        __builtin_amdgcn_sched_barrier(0);
        MFMA_Q(3);
        if (t < 15) { asm volatile("s_waitcnt vmcnt(2)" ::: "memory"); }
        __builtin_amdgcn_s_barrier();
    }
#undef MFMA_Q

    // ---------- fused y epilogue: y = h @ C_W on this tile (K = 64) ----------
    const int b64 = (m0 >> 12) * 64;
    const int sb0 = m0 & 4095;
    // Bs[0] <- Ct rows n0..n0+255 (gload_lds, pre-swizzled source)
#pragma unroll
    for (int p = 0; p < 4; ++p) {
        int c = p * 512 + wave * 64 + lane;
        int row = c >> 3;
        int col = (((c & 7) ^ (row & 7)) << 3);
        gload_lds16(Ct + (size_t)(n0 + row) * 64 + col,
                    &Bs[0][(p * 512 + wave * 64) * 8]);
    }
    // As[0] <- transpose(hT): As[m_local][kn], swizzled ds_writes
#pragma unroll
    for (int p = 0; p < 4; ++p) {
        int c = tid + p * 512;           // 2048 chunks: kn = c>>5, mc = c&31
        int kn = c >> 5, mc = c & 31;
        short8 v = *(const short8*)(hT + (size_t)(b64 + kn) * 4096 + sb0 + mc * 8);
#pragma unroll
        for (int j = 0; j < 8; ++j)
            As[0][SWIDX(mc * 8 + j, kn)] = (ushort_t)v[j];
    }
    __syncthreads();

    short8 by[4][2];
#pragma unroll
    for (int fn = 0; fn < 4; fn++)
#pragma unroll
        for (int kk = 0; kk < 2; kk++) {
            int r = wn * 64 + fn * 16 + lrow;
            by[fn][kk] = *(const short8*)&Bs[0][SWIDX(r, kk * 32 + lcol0)];
        }

#pragma unroll
    for (int g = 0; g < 4; g++) {        // register-sliced: 2 m-frags at a time
        f32x4 ty[2][4];
#pragma unroll
        for (int mm = 0; mm < 2; mm++)
#pragma unroll
            for (int fn = 0; fn < 4; fn++) { f32x4 z = {0.f,0.f,0.f,0.f}; ty[mm][fn] = z; }
#pragma unroll
        for (int mm = 0; mm < 2; mm++) {
            int r = g * 64 + wm * 32 + mm * 16 + lrow;
            short8 a0 = *(const short8*)&As[0][SWIDX(r, lcol0)];
            short8 a1 = *(const short8*)&As[0][SWIDX(r, 32 + lcol0)];
#pragma unroll
            for (int fn = 0; fn < 4; fn++) {
                ty[mm][fn] = __builtin_amdgcn_mfma_f32_16x16x32_bf16(a0, by[fn][0], ty[mm][fn], 0, 0, 0);
                ty[mm][fn] = __builtin_amdgcn_mfma_f32_16x16x32_bf16(a1, by[fn][1], ty[mm][fn], 0, 0, 0);
            }
        }
#pragma unroll
        for (int mm = 0; mm < 2; mm++)
#pragma unroll
            for (int fn = 0; fn < 4; fn++) {
                int col = n0 + wn * 64 + fn * 16 + lrow;
                int rbase = m0 + g * 64 + wm * 32 + mm * 16 + ((lane >> 4) << 2);
#pragma unroll
                for (int r = 0; r < 4; r++) {
                    float og = 1.f / (1.f + __expf(-acc[g * 2 + mm][fn][r]));
                    out[(size_t)(rbase + r) * 1024 + col] = ty[mm][fn][r] * og;
                }
            }
    }
}

// ---------------------------------------------------------------------------
extern "C" void kernel_launch(void* const* d_in, const int* in_sizes, int n_in,
                              void* d_out, int out_size, void* d_ws, size_t ws_size,
                              hipStream_t stream)
{
    const float* x      = (const float*)d_in[0];   // (4,4096,1024)
    const float* gate_W = (const float*)d_in[1];   // (1024,64)
    const float* gate_b = (const float*)d_in[2];   // (64,)
    const float* B_W    = (const float*)d_in[3];   // (1024,64)
    const float* C_W    = (const float*)d_in[4];   // (64,1024)
    const float* out_W  = (const float*)d_in[5];   // (1024,1024)
    // d_in[6] mix_weight cancels (h_next == h_final); d_in[7] chunk_size unused.
    float* out = (float*)d_out;

    char* ws = (char*)d_ws;
    float*    Zpart  = (float*)(ws + 0);            // 16 MiB [2][512][4096] fp32
    ushort_t* hT     = (ushort_t*)(ws + 16777216);  //  2 MiB [256][4096]
    ushort_t* x_hi   = (ushort_t*)(ws + 18874368);  // 32 MiB [16384][1024]
    ushort_t* W1t_hi = (ushort_t*)(ws + 52428800);  // [128][1024]
    ushort_t* W1t_lo = (ushort_t*)(ws + 52690944);
    ushort_t* outWt  = (ushort_t*)(ws + 52953088);  // [1024][1024]
    ushort_t* Ct     = (ushort_t*)(ws + 55050240);  // [1024][64]

    prep_weights<<<512, 256, 0, stream>>>(gate_W, B_W, C_W, out_W,
                                          W1t_hi, W1t_lo, outWt, Ct);

    p1_kernel<<<dim3(256, 2), 256, 0, stream>>>(x, W1t_hi, W1t_lo, x_hi, Zpart);

    scan_kernel<<<256, 256, 0, stream>>>(Zpart, gate_b, hT);

    gemm_out256<<<256, 512, 0, stream>>>(x_hi, outWt, hT, Ct, out);
}

// Round 11
// 83.948 us; speedup vs baseline: 1.1858x; 1.0942x over previous
//
#include <hip/hip_runtime.h>
#include <stdint.h>

typedef __attribute__((ext_vector_type(8))) short short8;      // 8 x bf16 (MFMA A/B frag)
typedef __attribute__((ext_vector_type(4))) float f32x4;       // MFMA acc frag
typedef __attribute__((ext_vector_type(4))) float f4;
typedef __attribute__((ext_vector_type(4))) unsigned short us4;

typedef unsigned short ushort_t;

__device__ __forceinline__ ushort_t f2bf(float f) {
    union { float f; uint32_t u; } c; c.f = f;
    uint32_t u = c.u;
    uint32_t r = u + 0x7fffu + ((u >> 16) & 1u);   // RNE
    return (ushort_t)(r >> 16);
}
__device__ __forceinline__ float bf2f(ushort_t h) {
    union { uint32_t u; float f; } c; c.u = ((uint32_t)h) << 16;
    return c.f;
}

// async global->LDS, 16B per lane; LDS dest = wave-uniform base + lane*16
typedef const __attribute__((address_space(1))) unsigned int as1_uint;
typedef __attribute__((address_space(3))) unsigned int as3_uint;
__device__ __forceinline__ void gload_lds16(const void* g, void* l) {
    __builtin_amdgcn_global_load_lds((as1_uint*)g, (as3_uint*)l, 16, 0, 0);
}

// LDS tile [256 rows][64 cols] bf16, XOR-swizzled: element (r,c) lives at
// ushort index r*64 + (c ^ ((r&7)<<3)). LDS stays linear for global_load_lds;
// the inverse permutation is applied on the GLOBAL source chunk (rule #21).
#define SWIDX(r, c) ((r) * 64 + ((c) ^ (((r) & 7) << 3)))

// ---------------------------------------------------------------------------
// Weight prep: B^T ([N][K]) layouts.
// ---------------------------------------------------------------------------
__global__ void prep_weights(const float* __restrict__ gate_W, const float* __restrict__ B_W,
                             const float* __restrict__ C_W, const float* __restrict__ out_W,
                             ushort_t* __restrict__ W1t_hi, ushort_t* __restrict__ W1t_lo,
                             ushort_t* __restrict__ outWt, ushort_t* __restrict__ Ct)
{
    int idx = blockIdx.x * 256 + threadIdx.x;
    int stride = gridDim.x * 256;
    for (int i = idx; i < 1024 * 1024; i += stride) {
        int nn = i >> 10, kk = i & 1023;
        outWt[i] = f2bf(out_W[kk * 1024 + nn]);
    }
    for (int i = idx; i < 128 * 1024; i += stride) {
        int nn = i >> 10, kk = i & 1023;
        float v = (nn < 64) ? gate_W[kk * 64 + nn] : B_W[kk * 64 + (nn - 64)];
        ushort_t h = f2bf(v);
        W1t_hi[i] = h;
        W1t_lo[i] = f2bf(v - bf2f(h));
    }
    for (int i = idx; i < 1024 * 64; i += stride) {
        int nn = i >> 6, kk = i & 63;
        Ct[i] = f2bf(C_W[kk * 1024 + nn]);
    }
}

// ---------------------------------------------------------------------------
// P1: Z^T[n][s] = sum_k W1[k][n] * x[s][k], 2-PASS split precision.
// Split-K (2 chunks of 512). Writes x_hi (bf16 of x) as a staging byproduct.
// ---------------------------------------------------------------------------
__global__ __launch_bounds__(256, 2)
void p1_kernel(const float* __restrict__ x,
               const ushort_t* __restrict__ W1t_hi, const ushort_t* __restrict__ W1t_lo,
               ushort_t* __restrict__ x_hi, float* __restrict__ Zpart)
{
    __shared__ ushort_t Ash[128 * 64];
    __shared__ ushort_t Asl[128 * 64];
    __shared__ ushort_t Bsh[64 * 64];

    const int tid = threadIdx.x;
    const int wave = tid >> 6, lane = tid & 63;
    const int wm = wave >> 1, wn = wave & 1;
    const int s0 = blockIdx.x * 64;
    const int kc = blockIdx.y;

    f32x4 acc[4][2];
#pragma unroll
    for (int i = 0; i < 4; i++)
#pragma unroll
        for (int j = 0; j < 2; j++) { f32x4 z = {0.f,0.f,0.f,0.f}; acc[i][j] = z; }

    for (int kt = 0; kt < 8; ++kt) {
        const int k0 = kc * 512 + kt * 64;
#pragma unroll
        for (int p = 0; p < 4; ++p) {
            int c = p * 256 + wave * 64 + lane;
            int row = c >> 3, col = (c & 7) * 8;
            gload_lds16(W1t_hi + (size_t)row * 1024 + k0 + col,
                        &Ash[(p * 256 + wave * 64) * 8]);
            gload_lds16(W1t_lo + (size_t)row * 1024 + k0 + col,
                        &Asl[(p * 256 + wave * 64) * 8]);
        }
#pragma unroll
        for (int p = 0; p < 4; ++p) {
            int f = tid + p * 256;
            int row = f >> 4, col = (f & 15) * 4;
            f4 v = *(const f4*)(x + (size_t)(s0 + row) * 1024 + k0 + col);
            us4 hi;
#pragma unroll
            for (int j = 0; j < 4; j++) hi[j] = f2bf(v[j]);
            *(us4*)&Bsh[row * 64 + col] = hi;
            *(us4*)(x_hi + (size_t)(s0 + row) * 1024 + k0 + col) = hi;
        }
        __syncthreads();
#pragma unroll
        for (int kk = 0; kk < 2; ++kk) {
            const int kb = kk * 32 + (lane >> 4) * 8;
            short8 ah[4], al[4], bh[2];
#pragma unroll
            for (int fm = 0; fm < 4; fm++) {
                int r = wm * 64 + fm * 16 + (lane & 15);
                ah[fm] = *(const short8*)&Ash[r * 64 + kb];
                al[fm] = *(const short8*)&Asl[r * 64 + kb];
            }
#pragma unroll
            for (int fn = 0; fn < 2; fn++) {
                int r = wn * 32 + fn * 16 + (lane & 15);
                bh[fn] = *(const short8*)&Bsh[r * 64 + kb];
            }
#pragma unroll
            for (int fm = 0; fm < 4; fm++)
#pragma unroll
                for (int fn = 0; fn < 2; fn++) {
                    acc[fm][fn] = __builtin_amdgcn_mfma_f32_16x16x32_bf16(ah[fm], bh[fn], acc[fm][fn], 0, 0, 0);
                    acc[fm][fn] = __builtin_amdgcn_mfma_f32_16x16x32_bf16(al[fm], bh[fn], acc[fm][fn], 0, 0, 0);
                }
        }
        __syncthreads();
    }
#pragma unroll
    for (int fm = 0; fm < 4; fm++) {
#pragma unroll
        for (int fn = 0; fn < 2; fn++) {
            int scol = s0 + wn * 32 + fn * 16 + (lane & 15);
            int b = scol >> 12, sb = scol & 4095;
            int nbase = wm * 64 + fm * 16 + ((lane >> 4) << 2);
#pragma unroll
            for (int r = 0; r < 4; r++) {
                Zpart[((size_t)kc * 512 + b * 128 + nbase + r) * 4096 + sb] = acc[fm][fn][r];
            }
        }
    }
}

// ---------------------------------------------------------------------------
// Scan: combine split-K partials, gate = sigmoid(zg+bias), h_t = a_t*h + b_t.
// Output hT[b*64+n][s] bf16.
// ---------------------------------------------------------------------------
__global__ __launch_bounds__(256)
void scan_kernel(const float* __restrict__ Zpart, const float* __restrict__ gate_b,
                 ushort_t* __restrict__ hT)
{
    __shared__ float SA[256], SB[256];
    const int bn = blockIdx.x;
    const int t = threadIdx.x;
    const int b = bn >> 6, n = bn & 63;
    const float gb = gate_b[n];
    const float* g0 = Zpart + ((size_t)(b * 128 + n)) * 4096;
    const float* g1 = g0 + (size_t)512 * 4096;
    const float* b0 = Zpart + ((size_t)(b * 128 + 64 + n)) * 4096;
    const float* b1 = b0 + (size_t)512 * 4096;
    const int sb = t * 16;

    float a[16], bb[16];
#pragma unroll
    for (int q = 0; q < 4; q++) {
        f4 vg0 = *(const f4*)(g0 + sb + q * 4);
        f4 vg1 = *(const f4*)(g1 + sb + q * 4);
        f4 vb0 = *(const f4*)(b0 + sb + q * 4);
        f4 vb1 = *(const f4*)(b1 + sb + q * 4);
#pragma unroll
        for (int j = 0; j < 4; j++) {
            a[q * 4 + j] = 1.f / (1.f + __expf(-(vg0[j] + vg1[j] + gb)));
            bb[q * 4 + j] = vb0[j] + vb1[j];
        }
    }
    float A = 1.f, Bv = 0.f;
#pragma unroll
    for (int i = 0; i < 16; i++) { Bv = a[i] * Bv + bb[i]; A *= a[i]; }
    SA[t] = A; SB[t] = Bv;
    __syncthreads();
    for (int off = 1; off < 256; off <<= 1) {
        float a1 = 1.f, b1v = 0.f;
        if (t >= off) { a1 = SA[t - off]; b1v = SB[t - off]; }
        float a2 = SA[t], b2 = SB[t];
        __syncthreads();
        SA[t] = a1 * a2;
        SB[t] = a2 * b1v + b2;
        __syncthreads();
    }
    float h = (t == 0) ? 0.f : SB[t - 1];
    ushort_t ov[16];
#pragma unroll
    for (int i = 0; i < 16; i++) {
        h = a[i] * h + bb[i];
        ov[i] = f2bf(h);
    }
    ushort_t* dst = hT + (size_t)bn * 4096 + sb;
#pragma unroll
    for (int q = 0; q < 4; q++) {
        us4 o; o[0]=ov[q*4]; o[1]=ov[q*4+1]; o[2]=ov[q*4+2]; o[3]=ov[q*4+3];
        *(us4*)(dst + q * 4) = o;
    }
}

// ---------------------------------------------------------------------------
// gemm_out256: out = (h@C_W) * sigmoid(x_hi @ outWt^T).
// R11: R9/R10 schedule + cross-phase A-quarter prefetch (parity regs aR0/aR1,
// counted lgkmcnt(4)) + vmcnt moved to end-q0/end-q2 + conflict-free epilogue
// transpose (kn per-lane). Stages still ONLY into buf^1.
// ---------------------------------------------------------------------------
__global__ __launch_bounds__(512, 2)
void gemm_out256(const ushort_t* __restrict__ x_hi, const ushort_t* __restrict__ outWt,
                 const ushort_t* __restrict__ hT, const ushort_t* __restrict__ Ct,
                 float* __restrict__ out)
{
    __shared__ ushort_t As[2][256 * 64];   // 64 KiB
    __shared__ ushort_t Bs[2][256 * 64];   // 64 KiB

    const int tid = threadIdx.x;
    const int wave = tid >> 6, lane = tid & 63;
    const int wm = wave >> 2;          // 0..1
    const int wn = wave & 3;           // 0..3

    // XCD chunking: XCD k (= flat&7) owns m-tiles 8k..8k+7, sweeps n within.
    const int flat = blockIdx.x;
    const int swz = (flat & 7) * 32 + (flat >> 3);
    const int m0 = (swz >> 2) * 256;
    const int n0 = (swz & 3) * 256;

    const int lcol0 = (lane >> 4) * 8;
    const int lrow = lane & 15;
    const int lxor = (lrow & 7) << 3;

    // per-lane LDS read offsets (elements); quarter = +q*4096
    const int aOff0 = (wm * 32 + lrow) * 64 + (lcol0 ^ lxor);
    const int aOff1 = (wm * 32 + lrow) * 64 + ((32 + lcol0) ^ lxor);
    const int bOff0 = (wn * 64 + lrow) * 64 + (lcol0 ^ lxor);
    const int bOff1 = (wn * 64 + lrow) * 64 + ((32 + lcol0) ^ lxor);

    // persistent global stage streams (advance +64 elements per stage)
    const int rl0 = tid >> 3;                       // 0..63
    const int col0 = ((tid & 7) ^ (rl0 & 7)) << 3;  // inverse-swizzled source
    const ushort_t* gB0a = outWt + (size_t)(n0 + rl0) * 1024 + col0;
    const ushort_t* gB0b = gB0a + 64 * 1024;
    const ushort_t* gB1a = outWt + (size_t)(n0 + 128 + rl0) * 1024 + col0;
    const ushort_t* gB1b = gB1a + 64 * 1024;
    const ushort_t* gA0a = x_hi + (size_t)(m0 + rl0) * 1024 + col0;
    const ushort_t* gA0b = gA0a + 64 * 1024;
    const ushort_t* gA1a = x_hi + (size_t)(m0 + 128 + rl0) * 1024 + col0;
    const ushort_t* gA1b = gA1a + 64 * 1024;

    auto STG = [&](const ushort_t*& ga, const ushort_t*& gb, ushort_t* ldsbase) {
        gload_lds16(ga, ldsbase + wave * 512);
        gload_lds16(gb, ldsbase + 4096 + wave * 512);
        ga += 64; gb += 64;
    };

    f32x4 acc[8][4];
#pragma unroll
    for (int i = 0; i < 8; i++)
#pragma unroll
        for (int j = 0; j < 4; j++) { f32x4 z = {0.f,0.f,0.f,0.f}; acc[i][j] = z; }

    // prologue: stage tile 0; retire B0,B1,A0 (A1 stays in flight); read quarter0.
    STG(gB0a, gB0b, &Bs[0][0]);
    STG(gB1a, gB1b, &Bs[0][8192]);
    STG(gA0a, gA0b, &As[0][0]);
    STG(gA1a, gA1b, &As[0][8192]);
    asm volatile("s_waitcnt vmcnt(2)" ::: "memory");
    __builtin_amdgcn_s_barrier();

    short8 aR0[2][2], aR1[2][2], bfr[4][2];
#pragma unroll
    for (int mm = 0; mm < 2; ++mm) {
        aR0[mm][0] = *(const short8*)&As[0][aOff0 + mm * 1024];
        aR0[mm][1] = *(const short8*)&As[0][aOff1 + mm * 1024];
    }

#define MFMA_Q(q, AR)                                                              \
    do {                                                                           \
        __builtin_amdgcn_s_setprio(1);                                             \
        _Pragma("unroll") for (int mm = 0; mm < 2; ++mm)                           \
            _Pragma("unroll") for (int fn = 0; fn < 4; ++fn) {                     \
                acc[2*(q)+mm][fn] = __builtin_amdgcn_mfma_f32_16x16x32_bf16(       \
                    AR[mm][0], bfr[fn][0], acc[2*(q)+mm][fn], 0, 0, 0);            \
                acc[2*(q)+mm][fn] = __builtin_amdgcn_mfma_f32_16x16x32_bf16(       \
                    AR[mm][1], bfr[fn][1], acc[2*(q)+mm][fn], 0, 0, 0);            \
            }                                                                      \
        __builtin_amdgcn_s_setprio(0);                                             \
    } while (0)

    for (int t = 0; t < 16; ++t) {
        const int bc = t & 1;
        const ushort_t* as = &As[bc][0];
        const ushort_t* bs = &Bs[bc][0];
        const ushort_t* asn = &As[bc ^ 1][0];

        // ---- q0: MFMA quarter0 (aR0); read B(t) + quarter1 -> aR1 ----
        if (t < 15) STG(gB0a, gB0b, &Bs[bc ^ 1][0]);           // B0(t+1)
#pragma unroll
        for (int fn = 0; fn < 4; ++fn) {
            bfr[fn][0] = *(const short8*)(bs + bOff0 + fn * 1024);
            bfr[fn][1] = *(const short8*)(bs + bOff1 + fn * 1024);
        }
#pragma unroll
        for (int mm = 0; mm < 2; ++mm) {
            aR1[mm][0] = *(const short8*)(as + aOff0 + 4096 + mm * 1024);
            aR1[mm][1] = *(const short8*)(as + aOff1 + 4096 + mm * 1024);
        }
        asm volatile("s_waitcnt lgkmcnt(4)" ::: "memory");
        __builtin_amdgcn_sched_barrier(0);
        MFMA_Q(0, aR0);
        if (t < 15) { asm volatile("s_waitcnt vmcnt(2)" ::: "memory"); }  // retire A1(t)
        else        { asm volatile("s_waitcnt vmcnt(0)" ::: "memory"); }
        __builtin_amdgcn_s_barrier();

        // ---- q1: MFMA quarter1 (aR1); read quarter2 -> aR0 ----
        if (t < 15) {
            STG(gB1a, gB1b, &Bs[bc ^ 1][8192]);                // B1(t+1)
            STG(gA0a, gA0b, &As[bc ^ 1][0]);                   // A0(t+1)
        }
#pragma unroll
        for (int mm = 0; mm < 2; ++mm) {
            aR0[mm][0] = *(const short8*)(as + aOff0 + 2 * 4096 + mm * 1024);
            aR0[mm][1] = *(const short8*)(as + aOff1 + 2 * 4096 + mm * 1024);
        }
        asm volatile("s_waitcnt lgkmcnt(4)" ::: "memory");
        __builtin_amdgcn_sched_barrier(0);
        MFMA_Q(1, aR1);
        __builtin_amdgcn_s_barrier();

        // ---- q2: MFMA quarter2 (aR0); read quarter3 -> aR1 ----
        if (t < 15) STG(gA1a, gA1b, &As[bc ^ 1][8192]);        // A1(t+1)
#pragma unroll
        for (int mm = 0; mm < 2; ++mm) {
            aR1[mm][0] = *(const short8*)(as + aOff0 + 3 * 4096 + mm * 1024);
            aR1[mm][1] = *(const short8*)(as + aOff1 + 3 * 4096 + mm * 1024);
        }
        asm volatile("s_waitcnt lgkmcnt(4)" ::: "memory");
        __builtin_amdgcn_sched_barrier(0);
        MFMA_Q(2, aR0);
        if (t < 15) { asm volatile("s_waitcnt vmcnt(2)" ::: "memory"); }  // retire B0,B1,A0(t+1)
        __builtin_amdgcn_s_barrier();

        // ---- q3: MFMA quarter3 (aR1); read quarter0(t+1) -> aR0 ----
        if (t < 15) {
#pragma unroll
            for (int mm = 0; mm < 2; ++mm) {
                aR0[mm][0] = *(const short8*)(asn + aOff0 + mm * 1024);
                aR0[mm][1] = *(const short8*)(asn + aOff1 + mm * 1024);
            }
            asm volatile("s_waitcnt lgkmcnt(4)" ::: "memory");
        } else {
            asm volatile("s_waitcnt lgkmcnt(0)" ::: "memory");
        }
        __builtin_amdgcn_sched_barrier(0);
        MFMA_Q(3, aR1);
        __builtin_amdgcn_s_barrier();
    }
#undef MFMA_Q

    // ---------- fused y epilogue: y = h @ C_W on this tile (K = 64) ----------
    const int b64 = (m0 >> 12) * 64;
    const int sb0 = m0 & 4095;
    // Bs[0] <- Ct rows n0..n0+255 (gload_lds, pre-swizzled source)
#pragma unroll
    for (int p = 0; p < 4; ++p) {
        int c = p * 512 + wave * 64 + lane;
        int row = c >> 3;
        int col = (((c & 7) ^ (row & 7)) << 3);
        gload_lds16(Ct + (size_t)(n0 + row) * 64 + col,
                    &Bs[0][(p * 512 + wave * 64) * 8]);
    }
    // As[0] <- transpose(hT). Conflict-free mapping: kn = c&63 (per-lane,
    // consecutive), mc = c>>6 (wave-uniform). All 64 lanes write ONE row at
    // 64 consecutive swizzled cols -> 2 lanes/bank = free. hT reads are 16B
    // scattered across 64 rows but L2-resident (512 KB/XCD slice).
#pragma unroll
    for (int p = 0; p < 4; ++p) {
        int c = tid + p * 512;           // kn = c&63, mc = c>>6 (0..31)
        int kn = c & 63, mc = c >> 6;
        short8 v = *(const short8*)(hT + (size_t)(b64 + kn) * 4096 + sb0 + mc * 8);
#pragma unroll
        for (int j = 0; j < 8; ++j)
            As[0][SWIDX(mc * 8 + j, kn)] = (ushort_t)v[j];
    }
    __syncthreads();

    short8 by[4][2];
#pragma unroll
    for (int fn = 0; fn < 4; fn++)
#pragma unroll
        for (int kk = 0; kk < 2; kk++) {
            int r = wn * 64 + fn * 16 + lrow;
            by[fn][kk] = *(const short8*)&Bs[0][SWIDX(r, kk * 32 + lcol0)];
        }

#pragma unroll
    for (int g = 0; g < 4; g++) {        // register-sliced: 2 m-frags at a time
        f32x4 ty[2][4];
#pragma unroll
        for (int mm = 0; mm < 2; mm++)
#pragma unroll
            for (int fn = 0; fn < 4; fn++) { f32x4 z = {0.f,0.f,0.f,0.f}; ty[mm][fn] = z; }
#pragma unroll
        for (int mm = 0; mm < 2; mm++) {
            int r = g * 64 + wm * 32 + mm * 16 + lrow;
            short8 a0 = *(const short8*)&As[0][SWIDX(r, lcol0)];
            short8 a1 = *(const short8*)&As[0][SWIDX(r, 32 + lcol0)];
#pragma unroll
            for (int fn = 0; fn < 4; fn++) {
                ty[mm][fn] = __builtin_amdgcn_mfma_f32_16x16x32_bf16(a0, by[fn][0], ty[mm][fn], 0, 0, 0);
                ty[mm][fn] = __builtin_amdgcn_mfma_f32_16x16x32_bf16(a1, by[fn][1], ty[mm][fn], 0, 0, 0);
            }
        }
#pragma unroll
        for (int mm = 0; mm < 2; mm++)
#pragma unroll
            for (int fn = 0; fn < 4; fn++) {
                int col = n0 + wn * 64 + fn * 16 + lrow;
                int rbase = m0 + g * 64 + wm * 32 + mm * 16 + ((lane >> 4) << 2);
#pragma unroll
                for (int r = 0; r < 4; r++) {
                    float og = 1.f / (1.f + __expf(-acc[g * 2 + mm][fn][r]));
                    out[(size_t)(rbase + r) * 1024 + col] = ty[mm][fn][r] * og;
                }
            }
    }
}

// ---------------------------------------------------------------------------
extern "C" void kernel_launch(void* const* d_in, const int* in_sizes, int n_in,
                              void* d_out, int out_size, void* d_ws, size_t ws_size,
                              hipStream_t stream)
{
    const float* x      = (const float*)d_in[0];   // (4,4096,1024)
    const float* gate_W = (const float*)d_in[1];   // (1024,64)
    const float* gate_b = (const float*)d_in[2];   // (64,)
    const float* B_W    = (const float*)d_in[3];   // (1024,64)
    const float* C_W    = (const float*)d_in[4];   // (64,1024)
    const float* out_W  = (const float*)d_in[5];   // (1024,1024)
    // d_in[6] mix_weight cancels (h_next == h_final); d_in[7] chunk_size unused.
    float* out = (float*)d_out;

    char* ws = (char*)d_ws;
    float*    Zpart  = (float*)(ws + 0);            // 16 MiB [2][512][4096] fp32
    ushort_t* hT     = (ushort_t*)(ws + 16777216);  //  2 MiB [256][4096]
    ushort_t* x_hi   = (ushort_t*)(ws + 18874368);  // 32 MiB [16384][1024]
    ushort_t* W1t_hi = (ushort_t*)(ws + 52428800);  // [128][1024]
    ushort_t* W1t_lo = (ushort_t*)(ws + 52690944);
    ushort_t* outWt  = (ushort_t*)(ws + 52953088);  // [1024][1024]
    ushort_t* Ct     = (ushort_t*)(ws + 55050240);  // [1024][64]

    prep_weights<<<512, 256, 0, stream>>>(gate_W, B_W, C_W, out_W,
                                          W1t_hi, W1t_lo, outWt, Ct);

    p1_kernel<<<dim3(256, 2), 256, 0, stream>>>(x, W1t_hi, W1t_lo, x_hi, Zpart);

    scan_kernel<<<256, 256, 0, stream>>>(Zpart, gate_b, hT);

    gemm_out256<<<256, 512, 0, stream>>>(x_hi, outWt, hT, Ct, out);
}